// Round 2
// baseline (330.861 us; speedup 1.0000x reference)
//
#include <hip/hip_runtime.h>
#include <hip/hip_bf16.h>
#include <stdint.h>

// Problem constants: B=128, S=512, I=128, Hd=512, G=3*Hd=1536, M=B*S=65536.
// All inputs/outputs are FP32 (reference uses jnp.float32). We convert
// x/w_emb/w_ih to bf16 once, run bf16 MFMA GEMMs w/ fp32 accumulate,
// store fp32 output.
#define M_TOT   65536
#define I_DIM   128
#define HD      512
#define HOFF    33488896   // 128*511*512, element offset of h_last in d_out
#define HROW    261632     // 511*512, per-b row stride of H

typedef __bf16 bf16x8 __attribute__((ext_vector_type(8)));
typedef float f32x4 __attribute__((ext_vector_type(4)));

struct __align__(8) bf16x4_t { __hip_bfloat16 v[4]; };

// async global->LDS, 16B per lane. LDS dest is wave-uniform base; HW scatters
// to base + lane*16 (m104/m108 semantics).
__device__ __forceinline__ void async_load16(const void* g, void* l) {
  __builtin_amdgcn_global_load_lds(
      (const __attribute__((address_space(1))) void*)g,
      (__attribute__((address_space(3))) void*)l, 16, 0, 0);
}

__device__ __forceinline__ float sigf(float x) {
  return 1.0f / (1.0f + __expf(-x));
}
__device__ __forceinline__ float tanhfast(float x) {
  return 1.0f - 2.0f / (__expf(2.0f * x) + 1.0f);
}

// ---------------------------------------------------------------------------
// fp32 -> bf16 conversion, 4 elements/thread (float4 load, 8B store).
// ---------------------------------------------------------------------------
__global__ void cvt_f32_bf16(const float* __restrict__ in,
                             __hip_bfloat16* __restrict__ out, int n4) {
  const int i = blockIdx.x * blockDim.x + threadIdx.x;
  if (i < n4) {
    const float4 v = ((const float4*)in)[i];
    bf16x4_t o;
    o.v[0] = __float2bfloat16(v.x);
    o.v[1] = __float2bfloat16(v.y);
    o.v[2] = __float2bfloat16(v.z);
    o.v[3] = __float2bfloat16(v.w);
    ((bf16x4_t*)out)[i] = o;
  }
}

// ---------------------------------------------------------------------------
// Kernel 1: emb[m,h] = sum_i x[m,i]*w_emb[h,i] + b_emb[h]   (bf16 out -> ws)
// M=65536, N=512, K=128. Tile 128x128, BK=64, 2 K-iters. 4 waves, 64x64 each.
// ---------------------------------------------------------------------------
__global__ __launch_bounds__(256, 2) void emb_gemm(
    const __hip_bfloat16* __restrict__ x,      // (65536,128) bf16 (ws)
    const __hip_bfloat16* __restrict__ w_emb,  // (512,128)  N x K, bf16 (ws)
    const float* __restrict__ b_emb,           // (512) fp32
    __hip_bfloat16* __restrict__ emb)          // (65536,512) bf16 (ws)
{
  __shared__ __align__(16) __hip_bfloat16 As[128 * 64];
  __shared__ __align__(16) __hip_bfloat16 Bs[128 * 64];

  const int tid  = threadIdx.x;
  const int w    = tid >> 6;
  const int lane = tid & 63;
  const int m0 = blockIdx.x * 128;
  const int n0 = blockIdx.y * 128;
  const int wm = (w >> 1) * 64;
  const int wn = (w & 1) * 64;
  const int lrow = lane >> 3;        // 0..7 (row within 8-row chunk)
  const int lcol = (lane & 7) * 8;   // element offset (8 bf16 = 16B)
  const int l15 = lane & 15;
  const int q   = lane >> 4;

  f32x4 acc[4][4];
#pragma unroll
  for (int i = 0; i < 4; ++i)
#pragma unroll
    for (int j = 0; j < 4; ++j) acc[i][j] = (f32x4)0.0f;

#pragma unroll
  for (int kk = 0; kk < 2; ++kk) {
    const int k0 = kk * 64;
#pragma unroll
    for (int c = 0; c < 4; ++c) {
      const int chunk = w * 4 + c;
      const int row = chunk * 8 + lrow;
      async_load16(x + (size_t)(m0 + row) * I_DIM + k0 + lcol,
                   (void*)&As[chunk * 8 * 64]);
      async_load16(w_emb + (size_t)(n0 + row) * I_DIM + k0 + lcol,
                   (void*)&Bs[chunk * 8 * 64]);
    }
    __syncthreads();
#pragma unroll
    for (int ks = 0; ks < 2; ++ks) {
      const int kb = ks * 32 + q * 8;
      bf16x8 af[4], bfr[4];
#pragma unroll
      for (int mi = 0; mi < 4; ++mi)
        af[mi] = *(const bf16x8*)&As[(wm + mi * 16 + l15) * 64 + kb];
#pragma unroll
      for (int ni = 0; ni < 4; ++ni)
        bfr[ni] = *(const bf16x8*)&Bs[(wn + ni * 16 + l15) * 64 + kb];
#pragma unroll
      for (int ni = 0; ni < 4; ++ni)
#pragma unroll
        for (int mi = 0; mi < 4; ++mi)
          acc[mi][ni] = __builtin_amdgcn_mfma_f32_16x16x32_bf16(
              af[mi], bfr[ni], acc[mi][ni], 0, 0, 0);
    }
    __syncthreads();
  }

  // epilogue: +b_emb, bf16 store. C/D layout: col=lane&15, row=q*4+reg (m89).
#pragma unroll
  for (int ni = 0; ni < 4; ++ni) {
    const int col = n0 + wn + ni * 16 + l15;
    const float bias = b_emb[col];
#pragma unroll
    for (int mi = 0; mi < 4; ++mi) {
#pragma unroll
      for (int r = 0; r < 4; ++r) {
        const int m = m0 + wm + mi * 16 + q * 4 + r;
        emb[(size_t)m * HD + col] = __float2bfloat16(acc[mi][ni][r] + bias);
      }
    }
  }
}

// ---------------------------------------------------------------------------
// Kernel 2: gi[m, g*512+h] = sum_h' emb[m,h']*w_ih[g*512+h, h'] ; gate math.
// Per block: 128 M-rows x 64 h-cols x 3 gates. BK=64, 8 K-iters.
// 4 waves (2x2): each wave 64(M) x 32(h) per gate -> acc[3][4][2].
// ---------------------------------------------------------------------------
__global__ __launch_bounds__(256, 2) void gru_gemm(
    const __hip_bfloat16* __restrict__ emb,   // (65536,512) bf16 (ws)
    const __hip_bfloat16* __restrict__ w_ih,  // (1536,512) N x K, bf16 (ws)
    const float* __restrict__ b_ih,           // (1536) fp32
    const float* __restrict__ b_hh,           // (1536) fp32
    float* __restrict__ out)                  // H(128,511,512) ++ h_last(128,512) fp32
{
  __shared__ __align__(16) __hip_bfloat16 As[128 * 64];       // 16 KB
  __shared__ __align__(16) __hip_bfloat16 Bs[3][64 * 64];     // 24 KB

  const int tid  = threadIdx.x;
  const int w    = tid >> 6;
  const int lane = tid & 63;
  const int m0 = blockIdx.x * 128;
  const int h0 = blockIdx.y * 64;
  const int wm = (w >> 1) * 64;
  const int wn = (w & 1) * 32;
  const int lrow = lane >> 3;
  const int lcol = (lane & 7) * 8;
  const int l15 = lane & 15;
  const int q   = lane >> 4;

  f32x4 acc[3][4][2];
#pragma unroll
  for (int g = 0; g < 3; ++g)
#pragma unroll
    for (int i = 0; i < 4; ++i)
#pragma unroll
      for (int j = 0; j < 2; ++j) acc[g][i][j] = (f32x4)0.0f;

  for (int kk = 0; kk < 8; ++kk) {
    const int k0 = kk * 64;
    // A tile: 128 rows -> 16 chunks, 4 per wave
#pragma unroll
    for (int c = 0; c < 4; ++c) {
      const int chunk = w * 4 + c;
      const int row = chunk * 8 + lrow;
      async_load16(emb + (size_t)(m0 + row) * HD + k0 + lcol,
                   (void*)&As[chunk * 8 * 64]);
    }
    // B tiles: per gate 64 rows -> 8 chunks, 2 per wave
#pragma unroll
    for (int g = 0; g < 3; ++g)
#pragma unroll
      for (int c = 0; c < 2; ++c) {
        const int chunk = w * 2 + c;
        const int row = chunk * 8 + lrow;
        async_load16(w_ih + (size_t)(g * HD + h0 + row) * HD + k0 + lcol,
                     (void*)&Bs[g][chunk * 8 * 64]);
      }
    __syncthreads();
#pragma unroll
    for (int ks = 0; ks < 2; ++ks) {
      const int kb = ks * 32 + q * 8;
      bf16x8 af[4];
#pragma unroll
      for (int mi = 0; mi < 4; ++mi)
        af[mi] = *(const bf16x8*)&As[(wm + mi * 16 + l15) * 64 + kb];
#pragma unroll
      for (int g = 0; g < 3; ++g)
#pragma unroll
        for (int ni = 0; ni < 2; ++ni) {
          const bf16x8 bfr =
              *(const bf16x8*)&Bs[g][(wn + ni * 16 + l15) * 64 + kb];
#pragma unroll
          for (int mi = 0; mi < 4; ++mi)
            acc[g][mi][ni] = __builtin_amdgcn_mfma_f32_16x16x32_bf16(
                af[mi], bfr, acc[g][mi][ni], 0, 0, 0);
        }
    }
    __syncthreads();
  }

  // epilogue: gates + scatter store (fp32).
#pragma unroll
  for (int ni = 0; ni < 2; ++ni) {
    const int col = h0 + wn + ni * 16 + l15;
    const float bir = b_ih[col];
    const float bhr = b_hh[col];
    const float biz = b_ih[HD + col];
    const float bhz = b_hh[HD + col];
    const float bin = b_ih[2 * HD + col];
    const float bhn = b_hh[2 * HD + col];
#pragma unroll
    for (int mi = 0; mi < 4; ++mi) {
#pragma unroll
      for (int r = 0; r < 4; ++r) {
        const int m = m0 + wm + mi * 16 + q * 4 + r;
        const float rr = sigf(acc[0][mi][ni][r] + bir + bhr);
        const float zz = sigf(acc[1][mi][ni][r] + biz + bhz);
        const float nn = tanhfast(acc[2][mi][ni][r] + bin + rr * bhn);
        const float hv = (1.0f - zz) * nn;
        const int b = m >> 9;       // m / 512
        const int s = m & 511;      // m % 512
        const size_t idx = (s < 511)
            ? (size_t)b * HROW + (size_t)s * HD + col
            : (size_t)HOFF + (size_t)b * HD + col;
        out[idx] = hv;
      }
    }
  }
}

extern "C" void kernel_launch(void* const* d_in, const int* in_sizes, int n_in,
                              void* d_out, int out_size, void* d_ws, size_t ws_size,
                              hipStream_t stream) {
  const float* x_f     = (const float*)d_in[0];   // (128,512,128)
  const float* w_emb_f = (const float*)d_in[1];   // (512,128)
  const float* b_emb   = (const float*)d_in[2];   // (512)
  const float* w_ih_f  = (const float*)d_in[3];   // (1536,512)
  const float* b_ih    = (const float*)d_in[4];   // (1536)
  const float* b_hh    = (const float*)d_in[5];   // (1536)
  float* out = (float*)d_out;

  // ws layout (bytes):
  //   [0, 64Mi)            emb bf16 (65536*512*2)
  //   [64Mi, +16Mi)        x bf16   (65536*128*2)
  //   [80Mi, +128Ki)       w_emb bf16
  //   [80Mi+128Ki, +1.5Mi) w_ih bf16
  char* ws = (char*)d_ws;
  __hip_bfloat16* emb_bf   = (__hip_bfloat16*)(ws);
  __hip_bfloat16* x_bf     = (__hip_bfloat16*)(ws + 67108864);
  __hip_bfloat16* w_emb_bf = (__hip_bfloat16*)(ws + 67108864 + 16777216);
  __hip_bfloat16* w_ih_bf  = (__hip_bfloat16*)(ws + 67108864 + 16777216 + 131072);

  // fp32 -> bf16 conversions (element counts all divisible by 4)
  {
    const int n4x = (M_TOT * I_DIM) / 4;       // 2097152
    cvt_f32_bf16<<<(n4x + 255) / 256, 256, 0, stream>>>(x_f, x_bf, n4x);
    const int n4we = (HD * I_DIM) / 4;         // 16384
    cvt_f32_bf16<<<(n4we + 255) / 256, 256, 0, stream>>>(w_emb_f, w_emb_bf, n4we);
    const int n4wi = (3 * HD * HD) / 4;        // 196608
    cvt_f32_bf16<<<(n4wi + 255) / 256, 256, 0, stream>>>(w_ih_f, w_ih_bf, n4wi);
  }

  emb_gemm<<<dim3(M_TOT / 128, HD / 128), 256, 0, stream>>>(
      x_bf, w_emb_bf, b_emb, emb_bf);
  gru_gemm<<<dim3(M_TOT / 128, HD / 64), 256, 0, stream>>>(
      emb_bf, w_ih_bf, b_ih, b_hh, out);
}

// Round 3
// 328.340 us; speedup vs baseline: 1.0077x; 1.0077x over previous
//
#include <hip/hip_runtime.h>
#include <hip/hip_bf16.h>
#include <stdint.h>

// Problem constants: B=128, S=512, I=128, Hd=512, G=3*Hd=1536, M=B*S=65536.
// Inputs/outputs FP32. Convert x/w_emb/w_ih to bf16 once (one fused kernel),
// bf16 MFMA GEMMs with fp32 accumulate, fp32 output.
#define M_TOT   65536
#define I_DIM   128
#define HD      512
#define HOFF    33488896   // 128*511*512, element offset of h_last in d_out
#define HROW    261632     // 511*512, per-b row stride of H

typedef __bf16 bf16x8 __attribute__((ext_vector_type(8)));
typedef float f32x4 __attribute__((ext_vector_type(4)));

struct __align__(8) bf16x4_t { __hip_bfloat16 v[4]; };

// async global->LDS, 16B per lane. LDS dest is wave-uniform base; HW scatters
// to base + lane*16 (m104/m108 semantics).
__device__ __forceinline__ void async_load16(const void* g, void* l) {
  __builtin_amdgcn_global_load_lds(
      (const __attribute__((address_space(1))) void*)g,
      (__attribute__((address_space(3))) void*)l, 16, 0, 0);
}

__device__ __forceinline__ float sigf(float x) {
  return 1.0f / (1.0f + __expf(-x));
}
__device__ __forceinline__ float tanhfast(float x) {
  return 1.0f - 2.0f / (__expf(2.0f * x) + 1.0f);
}

// ---------------------------------------------------------------------------
// Fused fp32 -> bf16 conversion for x, w_emb, w_ih (one launch).
// Index space is in float4 units over the concatenation.
// ---------------------------------------------------------------------------
#define N4_X   2097152                 // 65536*128/4
#define N4_WE  (N4_X + 16384)          // + 512*128/4
#define N4_WI  (N4_WE + 196608)        // + 1536*512/4
__global__ void cvt_all(const float* __restrict__ x,
                        const float* __restrict__ we,
                        const float* __restrict__ wi,
                        __hip_bfloat16* __restrict__ xb,
                        __hip_bfloat16* __restrict__ web,
                        __hip_bfloat16* __restrict__ wib) {
  const int i = blockIdx.x * blockDim.x + threadIdx.x;
  const float4* src;
  bf16x4_t* dst;
  int off;
  if (i < N4_X)       { src = (const float4*)x;  dst = (bf16x4_t*)xb;  off = i; }
  else if (i < N4_WE) { src = (const float4*)we; dst = (bf16x4_t*)web; off = i - N4_X; }
  else if (i < N4_WI) { src = (const float4*)wi; dst = (bf16x4_t*)wib; off = i - N4_WE; }
  else return;
  const float4 v = src[off];
  bf16x4_t o;
  o.v[0] = __float2bfloat16(v.x);
  o.v[1] = __float2bfloat16(v.y);
  o.v[2] = __float2bfloat16(v.z);
  o.v[3] = __float2bfloat16(v.w);
  dst[off] = o;
}

// ---------------------------------------------------------------------------
// Kernel 1: emb[m,h] = sum_i x[m,i]*w_emb[h,i] + b_emb[h]   (bf16 out -> ws)
// M=65536, N=512, K=128. Tile 128x128, BK=64, 2 K-iters. 4 waves, 64x64 each.
// Epilogue repacks through LDS so global stores are bf16x8 (16B/lane,
// 128B contiguous per 8-lane row group) instead of scalar 2B scatter.
// ---------------------------------------------------------------------------
__global__ __launch_bounds__(256, 2) void emb_gemm(
    const __hip_bfloat16* __restrict__ x,      // (65536,128) bf16 (ws)
    const __hip_bfloat16* __restrict__ w_emb,  // (512,128)  N x K, bf16 (ws)
    const float* __restrict__ b_emb,           // (512) fp32
    __hip_bfloat16* __restrict__ emb)          // (65536,512) bf16 (ws)
{
  __shared__ __align__(16) __hip_bfloat16 smem[2 * 128 * 64];  // As ++ Bs, 32KB
  __hip_bfloat16* As = smem;
  __hip_bfloat16* Bs = smem + 128 * 64;

  const int tid  = threadIdx.x;
  const int w    = tid >> 6;
  const int lane = tid & 63;
  const int m0 = blockIdx.x * 128;
  const int n0 = blockIdx.y * 128;
  const int wm = (w >> 1) * 64;
  const int wn = (w & 1) * 64;
  const int lrow = lane >> 3;        // 0..7 (row within 8-row chunk)
  const int lcol = (lane & 7) * 8;   // element offset (8 bf16 = 16B)
  const int l15 = lane & 15;
  const int q   = lane >> 4;

  f32x4 acc[4][4];
#pragma unroll
  for (int i = 0; i < 4; ++i)
#pragma unroll
    for (int j = 0; j < 4; ++j) acc[i][j] = (f32x4)0.0f;

#pragma unroll
  for (int kk = 0; kk < 2; ++kk) {
    const int k0 = kk * 64;
#pragma unroll
    for (int c = 0; c < 4; ++c) {
      const int chunk = w * 4 + c;
      const int row = chunk * 8 + lrow;
      async_load16(x + (size_t)(m0 + row) * I_DIM + k0 + lcol,
                   (void*)&As[chunk * 8 * 64]);
      async_load16(w_emb + (size_t)(n0 + row) * I_DIM + k0 + lcol,
                   (void*)&Bs[chunk * 8 * 64]);
    }
    __syncthreads();
#pragma unroll
    for (int ks = 0; ks < 2; ++ks) {
      const int kb = ks * 32 + q * 8;
      bf16x8 af[4], bfr[4];
#pragma unroll
      for (int mi = 0; mi < 4; ++mi)
        af[mi] = *(const bf16x8*)&As[(wm + mi * 16 + l15) * 64 + kb];
#pragma unroll
      for (int ni = 0; ni < 4; ++ni)
        bfr[ni] = *(const bf16x8*)&Bs[(wn + ni * 16 + l15) * 64 + kb];
#pragma unroll
      for (int ni = 0; ni < 4; ++ni)
#pragma unroll
        for (int mi = 0; mi < 4; ++mi)
          acc[mi][ni] = __builtin_amdgcn_mfma_f32_16x16x32_bf16(
              af[mi], bfr[ni], acc[mi][ni], 0, 0, 0);
    }
    __syncthreads();   // all LDS reads done -> safe to reuse smem in epilogue
  }

  // Epilogue: +b_emb, repack wave-private 64x64 tile through LDS, 16B stores.
  // C/D layout: col=lane&15, row=q*4+reg (m89).
  __hip_bfloat16* ebuf = &smem[w * 64 * 64];   // 8KB per wave, wave-private
#pragma unroll
  for (int ni = 0; ni < 4; ++ni) {
    const float bias = b_emb[n0 + wn + ni * 16 + l15];
#pragma unroll
    for (int mi = 0; mi < 4; ++mi)
#pragma unroll
      for (int r = 0; r < 4; ++r)
        ebuf[(mi * 16 + q * 4 + r) * 64 + ni * 16 + l15] =
            __float2bfloat16(acc[mi][ni][r] + bias);
  }
  // wave-private buffer: no barrier needed (compiler inserts lgkmcnt waits)
#pragma unroll
  for (int i = 0; i < 8; ++i) {
    const int row  = i * 8 + (lane >> 3);
    const int colb = (lane & 7) * 8;
    const bf16x8 v = *(const bf16x8*)&ebuf[row * 64 + colb];
    *(bf16x8*)&emb[(size_t)(m0 + wm + row) * HD + n0 + wn + colb] = v;
  }
}

// ---------------------------------------------------------------------------
// Kernel 2: gi[m, g*512+h] = sum_h' emb[m,h']*w_ih[g*512+h, h'] ; gate math.
// Per block: 128 M-rows x 64 h-cols x 3 gates. BK=64, 8 K-iters.
// 4 waves (2x2): each wave 64(M) x 32(h) per gate -> acc[3][4][2].
// ---------------------------------------------------------------------------
__global__ __launch_bounds__(256, 2) void gru_gemm(
    const __hip_bfloat16* __restrict__ emb,   // (65536,512) bf16 (ws)
    const __hip_bfloat16* __restrict__ w_ih,  // (1536,512) N x K, bf16 (ws)
    const float* __restrict__ b_ih,           // (1536) fp32
    const float* __restrict__ b_hh,           // (1536) fp32
    float* __restrict__ out)                  // H(128,511,512) ++ h_last(128,512) fp32
{
  __shared__ __align__(16) __hip_bfloat16 As[128 * 64];       // 16 KB
  __shared__ __align__(16) __hip_bfloat16 Bs[3][64 * 64];     // 24 KB

  const int tid  = threadIdx.x;
  const int w    = tid >> 6;
  const int lane = tid & 63;
  const int m0 = blockIdx.x * 128;
  const int h0 = blockIdx.y * 64;
  const int wm = (w >> 1) * 64;
  const int wn = (w & 1) * 32;
  const int lrow = lane >> 3;
  const int lcol = (lane & 7) * 8;
  const int l15 = lane & 15;
  const int q   = lane >> 4;

  f32x4 acc[3][4][2];
#pragma unroll
  for (int g = 0; g < 3; ++g)
#pragma unroll
    for (int i = 0; i < 4; ++i)
#pragma unroll
      for (int j = 0; j < 2; ++j) acc[g][i][j] = (f32x4)0.0f;

  for (int kk = 0; kk < 8; ++kk) {
    const int k0 = kk * 64;
    // A tile: 128 rows -> 16 chunks, 4 per wave
#pragma unroll
    for (int c = 0; c < 4; ++c) {
      const int chunk = w * 4 + c;
      const int row = chunk * 8 + lrow;
      async_load16(emb + (size_t)(m0 + row) * HD + k0 + lcol,
                   (void*)&As[chunk * 8 * 64]);
    }
    // B tiles: per gate 64 rows -> 8 chunks, 2 per wave
#pragma unroll
    for (int g = 0; g < 3; ++g)
#pragma unroll
      for (int c = 0; c < 2; ++c) {
        const int chunk = w * 2 + c;
        const int row = chunk * 8 + lrow;
        async_load16(w_ih + (size_t)(g * HD + h0 + row) * HD + k0 + lcol,
                     (void*)&Bs[g][chunk * 8 * 64]);
      }
    __syncthreads();
#pragma unroll
    for (int ks = 0; ks < 2; ++ks) {
      const int kb = ks * 32 + q * 8;
      bf16x8 af[4];
#pragma unroll
      for (int mi = 0; mi < 4; ++mi)
        af[mi] = *(const bf16x8*)&As[(wm + mi * 16 + l15) * 64 + kb];
#pragma unroll
      for (int g = 0; g < 3; ++g)
#pragma unroll
        for (int ni = 0; ni < 2; ++ni) {
          const bf16x8 bfr =
              *(const bf16x8*)&Bs[g][(wn + ni * 16 + l15) * 64 + kb];
#pragma unroll
          for (int mi = 0; mi < 4; ++mi)
            acc[g][mi][ni] = __builtin_amdgcn_mfma_f32_16x16x32_bf16(
                af[mi], bfr, acc[g][mi][ni], 0, 0, 0);
        }
    }
    __syncthreads();
  }

  // epilogue: gates + scatter store (fp32).
#pragma unroll
  for (int ni = 0; ni < 2; ++ni) {
    const int col = h0 + wn + ni * 16 + l15;
    const float bir = b_ih[col];
    const float bhr = b_hh[col];
    const float biz = b_ih[HD + col];
    const float bhz = b_hh[HD + col];
    const float bin = b_ih[2 * HD + col];
    const float bhn = b_hh[2 * HD + col];
#pragma unroll
    for (int mi = 0; mi < 4; ++mi) {
#pragma unroll
      for (int r = 0; r < 4; ++r) {
        const int m = m0 + wm + mi * 16 + q * 4 + r;
        const float rr = sigf(acc[0][mi][ni][r] + bir + bhr);
        const float zz = sigf(acc[1][mi][ni][r] + biz + bhz);
        const float nn = tanhfast(acc[2][mi][ni][r] + bin + rr * bhn);
        const float hv = (1.0f - zz) * nn;
        const int b = m >> 9;       // m / 512
        const int s = m & 511;      // m % 512
        const size_t idx = (s < 511)
            ? (size_t)b * HROW + (size_t)s * HD + col
            : (size_t)HOFF + (size_t)b * HD + col;
        out[idx] = hv;
      }
    }
  }
}

extern "C" void kernel_launch(void* const* d_in, const int* in_sizes, int n_in,
                              void* d_out, int out_size, void* d_ws, size_t ws_size,
                              hipStream_t stream) {
  const float* x_f     = (const float*)d_in[0];   // (128,512,128)
  const float* w_emb_f = (const float*)d_in[1];   // (512,128)
  const float* b_emb   = (const float*)d_in[2];   // (512)
  const float* w_ih_f  = (const float*)d_in[3];   // (1536,512)
  const float* b_ih    = (const float*)d_in[4];   // (1536)
  const float* b_hh    = (const float*)d_in[5];   // (1536)
  float* out = (float*)d_out;

  // ws layout (bytes):
  //   [0, 64Mi)            emb bf16 (65536*512*2)
  //   [64Mi, +16Mi)        x bf16   (65536*128*2)
  //   [80Mi, +128Ki)       w_emb bf16
  //   [80Mi+128Ki, +1.5Mi) w_ih bf16
  char* ws = (char*)d_ws;
  __hip_bfloat16* emb_bf   = (__hip_bfloat16*)(ws);
  __hip_bfloat16* x_bf     = (__hip_bfloat16*)(ws + 67108864);
  __hip_bfloat16* w_emb_bf = (__hip_bfloat16*)(ws + 67108864 + 16777216);
  __hip_bfloat16* w_ih_bf  = (__hip_bfloat16*)(ws + 67108864 + 16777216 + 131072);

  cvt_all<<<(N4_WI + 255) / 256, 256, 0, stream>>>(
      x_f, w_emb_f, w_ih_f, x_bf, w_emb_bf, w_ih_bf);

  emb_gemm<<<dim3(M_TOT / 128, HD / 128), 256, 0, stream>>>(
      x_bf, w_emb_bf, b_emb, emb_bf);
  gru_gemm<<<dim3(M_TOT / 128, HD / 64), 256, 0, stream>>>(
      emb_bf, w_ih_bf, b_ih, b_hh, out);
}

// Round 4
// 293.415 us; speedup vs baseline: 1.1276x; 1.1190x over previous
//
#include <hip/hip_runtime.h>
#include <hip/hip_bf16.h>
#include <stdint.h>

// Problem constants: B=128, S=512, I=128, Hd=512, G=3*Hd=1536, M=B*S=65536.
// Inputs/outputs FP32. Convert x/w_emb/w_ih to bf16 once (one fused kernel),
// bf16 MFMA GEMMs with fp32 accumulate, fp32 output.
#define M_TOT   65536
#define I_DIM   128
#define HD      512
#define HOFF    33488896   // 128*511*512, element offset of h_last in d_out
#define HROW    261632     // 511*512, per-b row stride of H

typedef __bf16 bf16x8 __attribute__((ext_vector_type(8)));
typedef float f32x4 __attribute__((ext_vector_type(4)));

struct __align__(8) bf16x4_t { __hip_bfloat16 v[4]; };

// async global->LDS, 16B per lane. LDS dest is wave-uniform base; HW scatters
// to base + lane*16 (m104/m108 semantics).
__device__ __forceinline__ void async_load16(const void* g, void* l) {
  __builtin_amdgcn_global_load_lds(
      (const __attribute__((address_space(1))) void*)g,
      (__attribute__((address_space(3))) void*)l, 16, 0, 0);
}

// v_rcp_f32: ~1ulp*4 rel err 2^-22 — far below the 1.4e-2 abs threshold.
__device__ __forceinline__ float fastrcp(float x) {
  return __builtin_amdgcn_rcpf(x);
}
__device__ __forceinline__ float sigf(float x) {
  return fastrcp(1.0f + __expf(-x));
}
__device__ __forceinline__ float tanhfast(float x) {
  return 1.0f - 2.0f * fastrcp(__expf(2.0f * x) + 1.0f);
}

// ---------------------------------------------------------------------------
// Fused fp32 -> bf16 conversion for x, w_emb, w_ih (one launch).
// Index space is in float4 units over the concatenation.
// ---------------------------------------------------------------------------
#define N4_X   2097152                 // 65536*128/4
#define N4_WE  (N4_X + 16384)          // + 512*128/4
#define N4_WI  (N4_WE + 196608)        // + 1536*512/4
__global__ void cvt_all(const float* __restrict__ x,
                        const float* __restrict__ we,
                        const float* __restrict__ wi,
                        __hip_bfloat16* __restrict__ xb,
                        __hip_bfloat16* __restrict__ web,
                        __hip_bfloat16* __restrict__ wib) {
  const int i = blockIdx.x * blockDim.x + threadIdx.x;
  const float4* src;
  bf16x4_t* dst;
  int off;
  if (i < N4_X)       { src = (const float4*)x;  dst = (bf16x4_t*)xb;  off = i; }
  else if (i < N4_WE) { src = (const float4*)we; dst = (bf16x4_t*)web; off = i - N4_X; }
  else if (i < N4_WI) { src = (const float4*)wi; dst = (bf16x4_t*)wib; off = i - N4_WE; }
  else return;
  const float4 v = src[off];
  bf16x4_t o;
  o.v[0] = __float2bfloat16(v.x);
  o.v[1] = __float2bfloat16(v.y);
  o.v[2] = __float2bfloat16(v.z);
  o.v[3] = __float2bfloat16(v.w);
  dst[off] = o;
}

// ---------------------------------------------------------------------------
// Kernel 1: emb[m,h] = sum_i x[m,i]*w_emb[h,i] + b_emb[h]   (bf16 out -> ws)
// M=65536, N=512, K=128. Tile 128x128, BK=64, 2 K-iters. 4 waves, 64x64 each.
// Epilogue repacks through LDS so global stores are bf16x8 (16B/lane).
// ---------------------------------------------------------------------------
__global__ __launch_bounds__(256, 2) void emb_gemm(
    const __hip_bfloat16* __restrict__ x,      // (65536,128) bf16 (ws)
    const __hip_bfloat16* __restrict__ w_emb,  // (512,128)  N x K, bf16 (ws)
    const float* __restrict__ b_emb,           // (512) fp32
    __hip_bfloat16* __restrict__ emb)          // (65536,512) bf16 (ws)
{
  __shared__ __align__(16) __hip_bfloat16 smem[2 * 128 * 64];  // As ++ Bs, 32KB
  __hip_bfloat16* As = smem;
  __hip_bfloat16* Bs = smem + 128 * 64;

  const int tid  = threadIdx.x;
  const int w    = tid >> 6;
  const int lane = tid & 63;
  const int m0 = blockIdx.x * 128;
  const int n0 = blockIdx.y * 128;
  const int wm = (w >> 1) * 64;
  const int wn = (w & 1) * 64;
  const int lrow = lane >> 3;        // 0..7 (row within 8-row chunk)
  const int lcol = (lane & 7) * 8;   // element offset (8 bf16 = 16B)
  const int l15 = lane & 15;
  const int q   = lane >> 4;

  f32x4 acc[4][4];
#pragma unroll
  for (int i = 0; i < 4; ++i)
#pragma unroll
    for (int j = 0; j < 4; ++j) acc[i][j] = (f32x4)0.0f;

#pragma unroll
  for (int kk = 0; kk < 2; ++kk) {
    const int k0 = kk * 64;
#pragma unroll
    for (int c = 0; c < 4; ++c) {
      const int chunk = w * 4 + c;
      const int row = chunk * 8 + lrow;
      async_load16(x + (size_t)(m0 + row) * I_DIM + k0 + lcol,
                   (void*)&As[chunk * 8 * 64]);
      async_load16(w_emb + (size_t)(n0 + row) * I_DIM + k0 + lcol,
                   (void*)&Bs[chunk * 8 * 64]);
    }
    __syncthreads();
#pragma unroll
    for (int ks = 0; ks < 2; ++ks) {
      const int kb = ks * 32 + q * 8;
      bf16x8 af[4], bfr[4];
#pragma unroll
      for (int mi = 0; mi < 4; ++mi)
        af[mi] = *(const bf16x8*)&As[(wm + mi * 16 + l15) * 64 + kb];
#pragma unroll
      for (int ni = 0; ni < 4; ++ni)
        bfr[ni] = *(const bf16x8*)&Bs[(wn + ni * 16 + l15) * 64 + kb];
#pragma unroll
      for (int ni = 0; ni < 4; ++ni)
#pragma unroll
        for (int mi = 0; mi < 4; ++mi)
          acc[mi][ni] = __builtin_amdgcn_mfma_f32_16x16x32_bf16(
              af[mi], bfr[ni], acc[mi][ni], 0, 0, 0);
    }
    __syncthreads();   // all LDS reads done -> safe to reuse smem in epilogue
  }

  // Epilogue: +b_emb, repack wave-private 64x64 tile through LDS, 16B stores.
  // C/D layout: col=lane&15, row=q*4+reg (m89).
  __hip_bfloat16* ebuf = &smem[w * 64 * 64];   // 8KB per wave, wave-private
#pragma unroll
  for (int ni = 0; ni < 4; ++ni) {
    const float bias = b_emb[n0 + wn + ni * 16 + l15];
#pragma unroll
    for (int mi = 0; mi < 4; ++mi)
#pragma unroll
      for (int r = 0; r < 4; ++r)
        ebuf[(mi * 16 + q * 4 + r) * 64 + ni * 16 + l15] =
            __float2bfloat16(acc[mi][ni][r] + bias);
  }
  // wave-private buffer: no barrier needed (compiler inserts lgkmcnt waits)
#pragma unroll
  for (int i = 0; i < 8; ++i) {
    const int row  = i * 8 + (lane >> 3);
    const int colb = (lane & 7) * 8;
    const bf16x8 v = *(const bf16x8*)&ebuf[row * 64 + colb];
    *(bf16x8*)&emb[(size_t)(m0 + wm + row) * HD + n0 + wn + colb] = v;
  }
}

// ---------------------------------------------------------------------------
// Kernel 2: gi[m, g*512+h] = sum_h' emb[m,h']*w_ih[g*512+h, h'] ; gate math.
// Per block: 128 M-rows x 64 h-cols x 3 gates. BK=64, 8 K-iters.
// 4 waves (2x2): each wave 64(M) x 32(h) per gate -> acc[3][4][2].
// Epilogue: gate math with v_rcp (no IEEE div), LDS repack, float4 stores.
// ---------------------------------------------------------------------------
__global__ __launch_bounds__(256, 2) void gru_gemm(
    const __hip_bfloat16* __restrict__ emb,   // (65536,512) bf16 (ws)
    const __hip_bfloat16* __restrict__ w_ih,  // (1536,512) N x K, bf16 (ws)
    const float* __restrict__ b_ih,           // (1536) fp32
    const float* __restrict__ b_hh,           // (1536) fp32
    float* __restrict__ out)                  // H(128,511,512) ++ h_last(128,512) fp32
{
  __shared__ __align__(16) char smem[40960];           // As 16K ++ Bs 24K
  __hip_bfloat16* As = (__hip_bfloat16*)smem;
  __hip_bfloat16* Bs = (__hip_bfloat16*)(smem + 16384);  // [3][64*64]

  const int tid  = threadIdx.x;
  const int w    = tid >> 6;
  const int lane = tid & 63;
  const int m0 = blockIdx.x * 128;
  const int h0 = blockIdx.y * 64;
  const int wm = (w >> 1) * 64;
  const int wn = (w & 1) * 32;
  const int lrow = lane >> 3;
  const int lcol = (lane & 7) * 8;
  const int l15 = lane & 15;
  const int q   = lane >> 4;

  f32x4 acc[3][4][2];
#pragma unroll
  for (int g = 0; g < 3; ++g)
#pragma unroll
    for (int i = 0; i < 4; ++i)
#pragma unroll
      for (int j = 0; j < 2; ++j) acc[g][i][j] = (f32x4)0.0f;

  for (int kk = 0; kk < 8; ++kk) {
    const int k0 = kk * 64;
    // A tile: 128 rows -> 16 chunks, 4 per wave
#pragma unroll
    for (int c = 0; c < 4; ++c) {
      const int chunk = w * 4 + c;
      const int row = chunk * 8 + lrow;
      async_load16(emb + (size_t)(m0 + row) * HD + k0 + lcol,
                   (void*)&As[chunk * 8 * 64]);
    }
    // B tiles: per gate 64 rows -> 8 chunks, 2 per wave
#pragma unroll
    for (int g = 0; g < 3; ++g)
#pragma unroll
      for (int c = 0; c < 2; ++c) {
        const int chunk = w * 2 + c;
        const int row = chunk * 8 + lrow;
        async_load16(w_ih + (size_t)(g * HD + h0 + row) * HD + k0 + lcol,
                     (void*)&Bs[g * 64 * 64 + chunk * 8 * 64]);
      }
    __syncthreads();
#pragma unroll
    for (int ks = 0; ks < 2; ++ks) {
      const int kb = ks * 32 + q * 8;
      bf16x8 af[4];
#pragma unroll
      for (int mi = 0; mi < 4; ++mi)
        af[mi] = *(const bf16x8*)&As[(wm + mi * 16 + l15) * 64 + kb];
#pragma unroll
      for (int g = 0; g < 3; ++g)
#pragma unroll
        for (int ni = 0; ni < 2; ++ni) {
          const bf16x8 bfr =
              *(const bf16x8*)&Bs[g * 64 * 64 + (wn + ni * 16 + l15) * 64 + kb];
#pragma unroll
          for (int mi = 0; mi < 4; ++mi)
            acc[g][mi][ni] = __builtin_amdgcn_mfma_f32_16x16x32_bf16(
                af[mi], bfr, acc[g][mi][ni], 0, 0, 0);
        }
    }
    __syncthreads();
  }

  // Epilogue: gate math (v_rcp), repack wave tile (64M x 32h fp32) through
  // LDS with stride 36 (conflict-free, 16B aligned), float4 stores.
  float* obuf = (float*)(smem + w * 9216);   // 64*36*4 = 9216 B per wave
#pragma unroll
  for (int ni = 0; ni < 2; ++ni) {
    const int col = h0 + wn + ni * 16 + l15;
    const float br = b_ih[col] + b_hh[col];
    const float bz = b_ih[HD + col] + b_hh[HD + col];
    const float bn = b_ih[2 * HD + col];
    const float bhn = b_hh[2 * HD + col];
#pragma unroll
    for (int mi = 0; mi < 4; ++mi) {
#pragma unroll
      for (int r = 0; r < 4; ++r) {
        const float rr = sigf(acc[0][mi][ni][r] + br);
        const float zz = sigf(acc[1][mi][ni][r] + bz);
        const float nn = tanhfast(acc[2][mi][ni][r] + bn + rr * bhn);
        obuf[(mi * 16 + q * 4 + r) * 36 + ni * 16 + l15] = (1.0f - zz) * nn;
      }
    }
  }
  // wave-private region: compiler-inserted lgkmcnt orders write->read
  const int srow = lane >> 3;        // 0..7
  const int scol = (lane & 7) * 4;   // 0,4,...,28
#pragma unroll
  for (int i = 0; i < 8; ++i) {
    const int row = i * 8 + srow;    // m_local 0..63
    const float4 v = *(const float4*)&obuf[row * 36 + scol];
    const int m = m0 + wm + row;
    const int b = m >> 9;            // m / 512
    const int s = m & 511;           // m % 512
    float* dst = (s < 511)
        ? out + (size_t)b * HROW + (size_t)s * HD + h0 + wn + scol
        : out + (size_t)HOFF + (size_t)b * HD + h0 + wn + scol;
    *(float4*)dst = v;
  }
}

extern "C" void kernel_launch(void* const* d_in, const int* in_sizes, int n_in,
                              void* d_out, int out_size, void* d_ws, size_t ws_size,
                              hipStream_t stream) {
  const float* x_f     = (const float*)d_in[0];   // (128,512,128)
  const float* w_emb_f = (const float*)d_in[1];   // (512,128)
  const float* b_emb   = (const float*)d_in[2];   // (512)
  const float* w_ih_f  = (const float*)d_in[3];   // (1536,512)
  const float* b_ih    = (const float*)d_in[4];   // (1536)
  const float* b_hh    = (const float*)d_in[5];   // (1536)
  float* out = (float*)d_out;

  // ws layout (bytes):
  //   [0, 64Mi)            emb bf16 (65536*512*2)
  //   [64Mi, +16Mi)        x bf16   (65536*128*2)
  //   [80Mi, +128Ki)       w_emb bf16
  //   [80Mi+128Ki, +1.5Mi) w_ih bf16
  char* ws = (char*)d_ws;
  __hip_bfloat16* emb_bf   = (__hip_bfloat16*)(ws);
  __hip_bfloat16* x_bf     = (__hip_bfloat16*)(ws + 67108864);
  __hip_bfloat16* w_emb_bf = (__hip_bfloat16*)(ws + 67108864 + 16777216);
  __hip_bfloat16* w_ih_bf  = (__hip_bfloat16*)(ws + 67108864 + 16777216 + 131072);

  cvt_all<<<(N4_WI + 255) / 256, 256, 0, stream>>>(
      x_f, w_emb_f, w_ih_f, x_bf, w_emb_bf, w_ih_bf);

  emb_gemm<<<dim3(M_TOT / 128, HD / 128), 256, 0, stream>>>(
      x_bf, w_emb_bf, b_emb, emb_bf);
  gru_gemm<<<dim3(M_TOT / 128, HD / 64), 256, 0, stream>>>(
      emb_bf, w_ih_bf, b_ih, b_hh, out);
}

// Round 6
// 286.217 us; speedup vs baseline: 1.1560x; 1.0251x over previous
//
#include <hip/hip_runtime.h>
#include <hip/hip_bf16.h>
#include <stdint.h>

// Problem constants: B=128, S=512, I=128, Hd=512, G=3*Hd=1536, M=B*S=65536.
// Inputs/outputs FP32. Convert x/w_emb/w_ih to bf16 once (one fused kernel),
// bf16 MFMA GEMMs with fp32 accumulate, fp32 output.
//
// LDS bank-conflict note: tile rows are 64 bf16 = 128 B = 32 banks, so
// unswizzled fragment reads are 16-way conflicted (R4: 3.2e7 conflict
// cycles = 36% of gru). global_load_lds pins LDS slot = base+lane*16, so we
// swizzle the GLOBAL source: LDS slot (row, s) holds global chunk s^(row&7).
#define M_TOT   65536
#define I_DIM   128
#define HD      512
#define HOFF    33488896   // 128*511*512, element offset of h_last in d_out
#define HROW    261632     // 511*512, per-b row stride of H

typedef __bf16 bf16x8 __attribute__((ext_vector_type(8)));
typedef float f32x4 __attribute__((ext_vector_type(4)));

struct __align__(8) bf16x4_t { __hip_bfloat16 v[4]; };

// async global->LDS, 16B per lane (lane-scatter base+lane*16, m104/m108).
__device__ __forceinline__ void async_load16(const void* g, void* l) {
  __builtin_amdgcn_global_load_lds(
      (const __attribute__((address_space(1))) void*)g,
      (__attribute__((address_space(3))) void*)l, 16, 0, 0);
}

// v_rcp_f32: rel err 2^-22 — far below the 1.4e-2 abs threshold.
__device__ __forceinline__ float fastrcp(float x) {
  return __builtin_amdgcn_rcpf(x);
}
__device__ __forceinline__ float sigf(float x) {
  return fastrcp(1.0f + __expf(-x));
}
__device__ __forceinline__ float tanhfast(float x) {
  return 1.0f - 2.0f * fastrcp(__expf(2.0f * x) + 1.0f);
}

// ---------------------------------------------------------------------------
// Fused fp32 -> bf16 conversion for x, w_emb, w_ih (one launch).
// ---------------------------------------------------------------------------
#define N4_X   2097152                 // 65536*128/4
#define N4_WE  (N4_X + 16384)          // + 512*128/4
#define N4_WI  (N4_WE + 196608)        // + 1536*512/4
__global__ void cvt_all(const float* __restrict__ x,
                        const float* __restrict__ we,
                        const float* __restrict__ wi,
                        __hip_bfloat16* __restrict__ xb,
                        __hip_bfloat16* __restrict__ web,
                        __hip_bfloat16* __restrict__ wib) {
  const int i = blockIdx.x * blockDim.x + threadIdx.x;
  const float4* src;
  bf16x4_t* dst;
  int off;
  if (i < N4_X)       { src = (const float4*)x;  dst = (bf16x4_t*)xb;  off = i; }
  else if (i < N4_WE) { src = (const float4*)we; dst = (bf16x4_t*)web; off = i - N4_X; }
  else if (i < N4_WI) { src = (const float4*)wi; dst = (bf16x4_t*)wib; off = i - N4_WE; }
  else return;
  const float4 v = src[off];
  bf16x4_t o;
  o.v[0] = __float2bfloat16(v.x);
  o.v[1] = __float2bfloat16(v.y);
  o.v[2] = __float2bfloat16(v.z);
  o.v[3] = __float2bfloat16(v.w);
  dst[off] = o;
}

// ---------------------------------------------------------------------------
// Kernel 1: emb[m,h] = sum_i x[m,i]*w_emb[h,i] + b_emb[h]   (bf16 out -> ws)
// M=65536, N=512, K=128. Tile 128x128, BK=64, 2 K-iters. 4 waves, 64x64 each.
// Swizzled staging (see top). Epilogue repacks through LDS, bf16x8 stores.
// ---------------------------------------------------------------------------
__global__ __launch_bounds__(256, 2) void emb_gemm(
    const __hip_bfloat16* __restrict__ x,      // (65536,128) bf16 (ws)
    const __hip_bfloat16* __restrict__ w_emb,  // (512,128)  N x K, bf16 (ws)
    const float* __restrict__ b_emb,           // (512) fp32
    __hip_bfloat16* __restrict__ emb)          // (65536,512) bf16 (ws)
{
  __shared__ __align__(16) __hip_bfloat16 smem[2 * 128 * 64];  // As ++ Bs, 32KB
  __hip_bfloat16* As = smem;
  __hip_bfloat16* Bs = smem + 128 * 64;

  const int tid  = threadIdx.x;
  const int w    = tid >> 6;
  const int lane = tid & 63;
  const int m0 = blockIdx.x * 128;
  const int n0 = blockIdx.y * 128;
  const int wm = (w >> 1) * 64;
  const int wn = (w & 1) * 64;
  const int lrow = lane >> 3;              // 0..7 (row within 8-row chunk)
  const int gc   = ((lane & 7) ^ lrow) * 8;  // swizzled global element offset
  const int l15 = lane & 15;
  const int q   = lane >> 4;
  const int sx  = l15 & 7;                 // row&7 for fragment rows

  f32x4 acc[4][4];
#pragma unroll
  for (int i = 0; i < 4; ++i)
#pragma unroll
    for (int j = 0; j < 4; ++j) acc[i][j] = (f32x4)0.0f;

#pragma unroll
  for (int kk = 0; kk < 2; ++kk) {
    const int k0 = kk * 64;
#pragma unroll
    for (int c = 0; c < 4; ++c) {
      const int chunk = w * 4 + c;
      const int row = chunk * 8 + lrow;
      async_load16(x + (size_t)(m0 + row) * I_DIM + k0 + gc,
                   (void*)&As[chunk * 8 * 64]);
      async_load16(w_emb + (size_t)(n0 + row) * I_DIM + k0 + gc,
                   (void*)&Bs[chunk * 8 * 64]);
    }
    __syncthreads();
#pragma unroll
    for (int ks = 0; ks < 2; ++ks) {
      const int s = ((ks * 4 + q) ^ sx) * 8;   // swizzled LDS chunk
      bf16x8 af[4], bfr[4];
#pragma unroll
      for (int mi = 0; mi < 4; ++mi)
        af[mi] = *(const bf16x8*)&As[(wm + mi * 16 + l15) * 64 + s];
#pragma unroll
      for (int ni = 0; ni < 4; ++ni)
        bfr[ni] = *(const bf16x8*)&Bs[(wn + ni * 16 + l15) * 64 + s];
#pragma unroll
      for (int ni = 0; ni < 4; ++ni)
#pragma unroll
        for (int mi = 0; mi < 4; ++mi)
          acc[mi][ni] = __builtin_amdgcn_mfma_f32_16x16x32_bf16(
              af[mi], bfr[ni], acc[mi][ni], 0, 0, 0);
    }
    __syncthreads();   // all LDS reads done -> safe to reuse smem in epilogue
  }

  // Epilogue: +b_emb, repack wave-private 64x64 tile through LDS, 16B stores.
  // C/D layout: col=lane&15, row=q*4+reg (m89).
  __hip_bfloat16* ebuf = &smem[w * 64 * 64];   // 8KB per wave, wave-private
#pragma unroll
  for (int ni = 0; ni < 4; ++ni) {
    const float bias = b_emb[n0 + wn + ni * 16 + l15];
#pragma unroll
    for (int mi = 0; mi < 4; ++mi)
#pragma unroll
      for (int r = 0; r < 4; ++r)
        ebuf[(mi * 16 + q * 4 + r) * 64 + ni * 16 + l15] =
            __float2bfloat16(acc[mi][ni][r] + bias);
  }
  // wave-private buffer: compiler-inserted lgkmcnt orders write->read
#pragma unroll
  for (int i = 0; i < 8; ++i) {
    const int row  = i * 8 + (lane >> 3);
    const int colb = (lane & 7) * 8;
    const bf16x8 v = *(const bf16x8*)&ebuf[row * 64 + colb];
    *(bf16x8*)&emb[(size_t)(m0 + wm + row) * HD + n0 + wn + colb] = v;
  }
}

// ---------------------------------------------------------------------------
// Kernel 2: gi[m, g*512+h] = sum_h' emb[m,h']*w_ih[g*512+h, h'] ; gate math.
// Per block: 128 M-rows x 64 h-cols x 3 gates. BK=64, 8 K-iters.
// 4 waves (2x2): each wave 64(M) x 32(h) per gate -> acc[3][4][2].
// Swizzled staging; epilogue: v_rcp gates, LDS repack stride 40, float4 out.
// ---------------------------------------------------------------------------
__global__ __launch_bounds__(256, 2) void gru_gemm(
    const __hip_bfloat16* __restrict__ emb,   // (65536,512) bf16 (ws)
    const __hip_bfloat16* __restrict__ w_ih,  // (1536,512) N x K, bf16 (ws)
    const float* __restrict__ b_ih,           // (1536) fp32
    const float* __restrict__ b_hh,           // (1536) fp32
    float* __restrict__ out)                  // H(128,511,512) ++ h_last(128,512) fp32
{
  __shared__ __align__(16) char smem[40960];           // As 16K ++ Bs 24K
  __hip_bfloat16* As = (__hip_bfloat16*)smem;
  __hip_bfloat16* Bs = (__hip_bfloat16*)(smem + 16384);  // [3][64*64]

  const int tid  = threadIdx.x;
  const int w    = tid >> 6;
  const int lane = tid & 63;
  const int m0 = blockIdx.x * 128;
  const int h0 = blockIdx.y * 64;
  const int wm = (w >> 1) * 64;
  const int wn = (w & 1) * 32;
  const int lrow = lane >> 3;
  const int gc   = ((lane & 7) ^ lrow) * 8;  // swizzled global element offset
  const int l15 = lane & 15;
  const int q   = lane >> 4;
  const int sx  = l15 & 7;

  f32x4 acc[3][4][2];
#pragma unroll
  for (int g = 0; g < 3; ++g)
#pragma unroll
    for (int i = 0; i < 4; ++i)
#pragma unroll
      for (int j = 0; j < 2; ++j) acc[g][i][j] = (f32x4)0.0f;

  for (int kk = 0; kk < 8; ++kk) {
    const int k0 = kk * 64;
    // A tile: 128 rows -> 16 chunks, 4 per wave
#pragma unroll
    for (int c = 0; c < 4; ++c) {
      const int chunk = w * 4 + c;
      const int row = chunk * 8 + lrow;
      async_load16(emb + (size_t)(m0 + row) * HD + k0 + gc,
                   (void*)&As[chunk * 8 * 64]);
    }
    // B tiles: per gate 64 rows -> 8 chunks, 2 per wave
#pragma unroll
    for (int g = 0; g < 3; ++g)
#pragma unroll
      for (int c = 0; c < 2; ++c) {
        const int chunk = w * 2 + c;
        const int row = chunk * 8 + lrow;
        async_load16(w_ih + (size_t)(g * HD + h0 + row) * HD + k0 + gc,
                     (void*)&Bs[g * 64 * 64 + chunk * 8 * 64]);
      }
    __syncthreads();
#pragma unroll
    for (int ks = 0; ks < 2; ++ks) {
      const int s = ((ks * 4 + q) ^ sx) * 8;   // swizzled LDS chunk
      bf16x8 af[4];
#pragma unroll
      for (int mi = 0; mi < 4; ++mi)
        af[mi] = *(const bf16x8*)&As[(wm + mi * 16 + l15) * 64 + s];
#pragma unroll
      for (int g = 0; g < 3; ++g)
#pragma unroll
        for (int ni = 0; ni < 2; ++ni) {
          const bf16x8 bfr =
              *(const bf16x8*)&Bs[g * 64 * 64 + (wn + ni * 16 + l15) * 64 + s];
#pragma unroll
          for (int mi = 0; mi < 4; ++mi)
            acc[g][mi][ni] = __builtin_amdgcn_mfma_f32_16x16x32_bf16(
                af[mi], bfr, acc[g][mi][ni], 0, 0, 0);
        }
    }
    __syncthreads();
  }

  // Epilogue: gate math (v_rcp), repack wave tile (64M x 32h fp32) through
  // LDS with stride 40 floats (40%32=8 -> 2-way on float4 reads = free),
  // float4 stores. 64*40*4 = 10240 B per wave, 4 waves = 40960 = smem.
  float* obuf = (float*)(smem + w * 10240);
#pragma unroll
  for (int ni = 0; ni < 2; ++ni) {
    const int col = h0 + wn + ni * 16 + l15;
    const float br = b_ih[col] + b_hh[col];
    const float bz = b_ih[HD + col] + b_hh[HD + col];
    const float bn = b_ih[2 * HD + col];
    const float bhn = b_hh[2 * HD + col];
#pragma unroll
    for (int mi = 0; mi < 4; ++mi) {
#pragma unroll
      for (int r = 0; r < 4; ++r) {
        const float rr = sigf(acc[0][mi][ni][r] + br);
        const float zz = sigf(acc[1][mi][ni][r] + bz);
        const float nn = tanhfast(acc[2][mi][ni][r] + bn + rr * bhn);
        obuf[(mi * 16 + q * 4 + r) * 40 + ni * 16 + l15] = (1.0f - zz) * nn;
      }
    }
  }
  // wave-private region: compiler-inserted lgkmcnt orders write->read
  const int srow = lane >> 3;        // 0..7
  const int scol = (lane & 7) * 4;   // 0,4,...,28
#pragma unroll
  for (int i = 0; i < 8; ++i) {
    const int row = i * 8 + srow;    // m_local 0..63
    const float4 v = *(const float4*)&obuf[row * 40 + scol];
    const int m = m0 + wm + row;
    const int b = m >> 9;            // m / 512
    const int s = m & 511;           // m % 512
    float* dst = (s < 511)
        ? out + (size_t)b * HROW + (size_t)s * HD + h0 + wn + scol
        : out + (size_t)HOFF + (size_t)b * HD + h0 + wn + scol;
    *(float4*)dst = v;
  }
}

extern "C" void kernel_launch(void* const* d_in, const int* in_sizes, int n_in,
                              void* d_out, int out_size, void* d_ws, size_t ws_size,
                              hipStream_t stream) {
  const float* x_f     = (const float*)d_in[0];   // (128,512,128)
  const float* w_emb_f = (const float*)d_in[1];   // (512,128)
  const float* b_emb   = (const float*)d_in[2];   // (512)
  const float* w_ih_f  = (const float*)d_in[3];   // (1536,512)
  const float* b_ih    = (const float*)d_in[4];   // (1536)
  const float* b_hh    = (const float*)d_in[5];   // (1536)
  float* out = (float*)d_out;

  // ws layout (bytes):
  //   [0, 64Mi)            emb bf16 (65536*512*2)
  //   [64Mi, +16Mi)        x bf16   (65536*128*2)
  //   [80Mi, +128Ki)       w_emb bf16
  //   [80Mi+128Ki, +1.5Mi) w_ih bf16
  char* ws = (char*)d_ws;
  __hip_bfloat16* emb_bf   = (__hip_bfloat16*)(ws);
  __hip_bfloat16* x_bf     = (__hip_bfloat16*)(ws + 67108864);
  __hip_bfloat16* w_emb_bf = (__hip_bfloat16*)(ws + 67108864 + 16777216);
  __hip_bfloat16* w_ih_bf  = (__hip_bfloat16*)(ws + 67108864 + 16777216 + 131072);

  cvt_all<<<(N4_WI + 255) / 256, 256, 0, stream>>>(
      x_f, w_emb_f, w_ih_f, x_bf, w_emb_bf, w_ih_bf);

  emb_gemm<<<dim3(M_TOT / 128, HD / 128), 256, 0, stream>>>(
      x_bf, w_emb_bf, b_emb, emb_bf);
  gru_gemm<<<dim3(M_TOT / 128, HD / 64), 256, 0, stream>>>(
      emb_bf, w_ih_bf, b_ih, b_hh, out);
}